// Round 1
// baseline (2050.313 us; speedup 1.0000x reference)
//
#include <hip/hip_runtime.h>
#include <stdint.h>

typedef float f32x4 __attribute__((ext_vector_type(4)));

constexpr int Mdim = 8192;    // B*S = 4*2048
constexpr int Ndim = 14336;
constexpr int Kdim = 4096;
constexpr int BM = 128, BN = 128, BK = 64;

__device__ __forceinline__ void gload_lds16(const void* g, void* l) {
  __builtin_amdgcn_global_load_lds(
      (const __attribute__((address_space(1))) unsigned int*)g,
      (__attribute__((address_space(3))) unsigned int*)l, 16, 0, 0);
}

// Quantize fp32 -> fp8 e4m3fn (OCP, RNE via v_cvt_pk_fp8_f32):
//   q = cast(clip(v / s, -448, 448)).  For the weight path scale_ptr==nullptr
//   (s = 1.0, conversion exact since values are e4m3 lattice points).
__global__ void __launch_bounds__(256) quant_fp8_kernel(
    const float* __restrict__ in, uint8_t* __restrict__ out8,
    const float* __restrict__ scale_ptr, long long n)
{
  const float s = scale_ptr ? scale_ptr[0] : 1.0f;
  const long long nch = n >> 3;  // 8 elems / thread / step
  const long long idx = (long long)blockIdx.x * blockDim.x + threadIdx.x;
  const long long stride = (long long)gridDim.x * blockDim.x;
  for (long long c = idx; c < nch; c += stride) {
    f32x4 v0 = *(const f32x4*)(in + c * 8);
    f32x4 v1 = *(const f32x4*)(in + c * 8 + 4);
    float q[8];
#pragma unroll
    for (int j = 0; j < 4; ++j) {
      q[j]     = fminf(fmaxf(v0[j] / s, -448.f), 448.f);
      q[4 + j] = fminf(fmaxf(v1[j] / s, -448.f), 448.f);
    }
    unsigned int w0 = 0, w1 = 0;
    w0 = __builtin_amdgcn_cvt_pk_fp8_f32(q[0], q[1], w0, false);
    w0 = __builtin_amdgcn_cvt_pk_fp8_f32(q[2], q[3], w0, true);
    w1 = __builtin_amdgcn_cvt_pk_fp8_f32(q[4], q[5], w1, false);
    w1 = __builtin_amdgcn_cvt_pk_fp8_f32(q[6], q[7], w1, true);
    uint2 r; r.x = w0; r.y = w1;
    *(uint2*)(out8 + c * 8) = r;
  }
}

// C = (A @ B^T) * alpha + bias.  A: [M][K] fp8, B: [N][K] fp8, C: [M][N] f32.
// 128x128 tile, BK=64, 4 waves (2x2), each wave 64x64 via 4x4 frags of
// mfma_f32_16x16x32_fp8_fp8.  global_load_lds width=16 staging (m97/m145
// structure).
__global__ void __launch_bounds__(256) gemm_fp8_kernel(
    const uint8_t* __restrict__ qa, const uint8_t* __restrict__ qb,
    const float* __restrict__ iscale, const float* __restrict__ wscale,
    const float* __restrict__ bias, float* __restrict__ out)
{
  __shared__ uint8_t As[BM * BK];
  __shared__ uint8_t Bs[BN * BK];

  const int tid  = threadIdx.x;
  const int wave = tid >> 6;
  const int lane = tid & 63;
  const int wm = wave >> 1;   // 0..1
  const int wn = wave & 1;    // 0..1
  const long long tile_m = (long long)blockIdx.y * BM;
  const long long tile_n = (long long)blockIdx.x * BN;

  // Staging: 512 16-byte segments per tile, 2 rounds of 256 threads.
  // Segment s -> row = s>>2, byte-col = (s&3)*16; LDS byte offset = s*16
  // (linear, matching global_load_lds's wave-uniform-base + lane*16 rule).
  const int s0 = wave * 64 + lane;
  const int s1 = s0 + 256;
  const int rA0 = s0 >> 2, c0 = (s0 & 3) * 16;
  const int rA1 = s1 >> 2, c1 = (s1 & 3) * 16;

  const uint8_t* ga0 = qa + (tile_m + rA0) * Kdim + c0;
  const uint8_t* ga1 = qa + (tile_m + rA1) * Kdim + c1;
  const uint8_t* gb0 = qb + (tile_n + rA0) * Kdim + c0;
  const uint8_t* gb1 = qb + (tile_n + rA1) * Kdim + c1;

  uint8_t* lA0 = As + wave * 1024;         // + implicit lane*16
  uint8_t* lA1 = As + 4096 + wave * 1024;
  uint8_t* lB0 = Bs + wave * 1024;
  uint8_t* lB1 = Bs + 4096 + wave * 1024;

  f32x4 acc[4][4] = {};

  const int lr = lane & 15;         // row (A) / col (B) within frag
  const int lk = (lane >> 4) * 8;   // k byte offset within 32-wide K slice

  for (int k0 = 0; k0 < Kdim; k0 += BK) {
    gload_lds16(ga0 + k0, lA0);
    gload_lds16(ga1 + k0, lA1);
    gload_lds16(gb0 + k0, lB0);
    gload_lds16(gb1 + k0, lB1);
    __syncthreads();   // compiler drains vmcnt before s_barrier

#pragma unroll
    for (int ks = 0; ks < 2; ++ks) {
      long long afr[4], bfr[4];
#pragma unroll
      for (int m = 0; m < 4; ++m)
        afr[m] = *(const long long*)(As + (wm * 64 + m * 16 + lr) * BK + ks * 32 + lk);
#pragma unroll
      for (int n = 0; n < 4; ++n)
        bfr[n] = *(const long long*)(Bs + (wn * 64 + n * 16 + lr) * BK + ks * 32 + lk);
#pragma unroll
      for (int m = 0; m < 4; ++m)
#pragma unroll
        for (int n = 0; n < 4; ++n)
          acc[m][n] = __builtin_amdgcn_mfma_f32_16x16x32_fp8_fp8(
              afr[m], bfr[n], acc[m][n], 0, 0, 0);
    }
    __syncthreads();   // protect LDS before next stage overwrites
  }

  const float alpha = iscale[0] * wscale[0];
  const long long col0 = tile_n + wn * 64 + lr;
  const long long row0 = tile_m + wm * 64 + (lane >> 4) * 4;
  float bv[4];
#pragma unroll
  for (int n = 0; n < 4; ++n) bv[n] = bias[col0 + n * 16];
#pragma unroll
  for (int m = 0; m < 4; ++m) {
#pragma unroll
    for (int r = 0; r < 4; ++r) {
      const long long row = row0 + m * 16 + r;
      float* op = out + row * (long long)Ndim + col0;
#pragma unroll
      for (int n = 0; n < 4; ++n)
        op[n * 16] = acc[m][n][r] * alpha + bv[n];
    }
  }
}

extern "C" void kernel_launch(void* const* d_in, const int* in_sizes, int n_in,
                              void* d_out, int out_size, void* d_ws, size_t ws_size,
                              hipStream_t stream) {
  const float* x      = (const float*)d_in[0];  // [4,2048,4096]
  const float* weight = (const float*)d_in[1];  // [14336,4096] (e4m3 lattice)
  const float* wscale = (const float*)d_in[2];  // [1]
  const float* iscale = (const float*)d_in[3];  // [1]
  const float* bias   = (const float*)d_in[4];  // [14336]
  float* out = (float*)d_out;                   // [4,2048,14336]

  uint8_t* qx = (uint8_t*)d_ws;                          // 32 MiB
  uint8_t* qw = qx + (long long)Mdim * Kdim;             // 56 MiB

  const long long nx = (long long)Mdim * Kdim;
  const long long nw = (long long)Ndim * Kdim;

  quant_fp8_kernel<<<4096, 256, 0, stream>>>(x, qx, iscale, nx);
  quant_fp8_kernel<<<4096, 256, 0, stream>>>(weight, qw, nullptr, nw);

  dim3 grid(Ndim / BN, Mdim / BM);
  gemm_fp8_kernel<<<grid, 256, 0, stream>>>(qx, qw, iscale, wscale, bias, out);
}

// Round 2
// 1210.132 us; speedup vs baseline: 1.6943x; 1.6943x over previous
//
#include <hip/hip_runtime.h>
#include <stdint.h>

typedef float f32x4 __attribute__((ext_vector_type(4)));

constexpr int Mdim = 8192;    // B*S = 4*2048
constexpr int Ndim = 14336;
constexpr int Kdim = 4096;
constexpr int BM = 128, BN = 128, BK = 64;

__device__ __forceinline__ void gload_lds16(const void* g, void* l) {
  __builtin_amdgcn_global_load_lds(
      (const __attribute__((address_space(1))) unsigned int*)g,
      (__attribute__((address_space(3))) unsigned int*)l, 16, 0, 0);
}

// Quantize fp32 -> fp8 e4m3fn (OCP, RNE via v_cvt_pk_fp8_f32):
//   q = cast(clip(v / s, -448, 448)).  For the weight path scale_ptr==nullptr
//   (s = 1.0, conversion exact since values are e4m3 lattice points).
__global__ void __launch_bounds__(256) quant_fp8_kernel(
    const float* __restrict__ in, uint8_t* __restrict__ out8,
    const float* __restrict__ scale_ptr, long long n)
{
  const float s = scale_ptr ? scale_ptr[0] : 1.0f;
  const long long nch = n >> 3;  // 8 elems / thread / step
  const long long idx = (long long)blockIdx.x * blockDim.x + threadIdx.x;
  const long long stride = (long long)gridDim.x * blockDim.x;
  for (long long c = idx; c < nch; c += stride) {
    f32x4 v0 = *(const f32x4*)(in + c * 8);
    f32x4 v1 = *(const f32x4*)(in + c * 8 + 4);
    float q[8];
#pragma unroll
    for (int j = 0; j < 4; ++j) {
      q[j]     = fminf(fmaxf(v0[j] / s, -448.f), 448.f);
      q[4 + j] = fminf(fmaxf(v1[j] / s, -448.f), 448.f);
    }
    unsigned int w0 = 0, w1 = 0;
    w0 = __builtin_amdgcn_cvt_pk_fp8_f32(q[0], q[1], w0, false);
    w0 = __builtin_amdgcn_cvt_pk_fp8_f32(q[2], q[3], w0, true);
    w1 = __builtin_amdgcn_cvt_pk_fp8_f32(q[4], q[5], w1, false);
    w1 = __builtin_amdgcn_cvt_pk_fp8_f32(q[6], q[7], w1, true);
    uint2 r; r.x = w0; r.y = w1;
    *(uint2*)(out8 + c * 8) = r;
  }
}

// C = (A @ B^T) * alpha + bias.  A: [M][K] fp8, B: [N][K] fp8, C: [M][N] f32.
// 128x128 tile, BK=64, 4 waves (2x2), each wave 64x64 via 4x4 frags of
// mfma_f32_16x16x32_fp8_fp8.  global_load_lds width=16 staging.
//
// T2 swizzle (bank-conflict fix): LDS logical byte (row, c) lives at
// row*64 + (c ^ ((row&3)<<4)).  Mask only touches bits [5:4] so each 16-byte
// global_load_lds segment remains one contiguous, 16-aligned global read:
// the SOURCE address is pre-swizzled, the LDS dest stays linear, and the
// ds_read applies the same XOR (both-sides involution, rule #21).
__global__ void __launch_bounds__(256) gemm_fp8_kernel(
    const uint8_t* __restrict__ qa, const uint8_t* __restrict__ qb,
    const float* __restrict__ iscale, const float* __restrict__ wscale,
    const float* __restrict__ bias, float* __restrict__ out)
{
  __shared__ uint8_t As[BM * BK];
  __shared__ uint8_t Bs[BN * BK];

  const int tid  = threadIdx.x;
  const int wave = tid >> 6;
  const int lane = tid & 63;
  const int wm = wave >> 1;   // 0..1
  const int wn = wave & 1;    // 0..1
  const long long tile_m = (long long)blockIdx.y * BM;
  const long long tile_n = (long long)blockIdx.x * BN;

  // Staging: 512 16-byte segments per tile, 2 rounds of 256 threads.
  // Segment s -> row = s>>2, colblock = s&3; LDS byte offset = s*16 (linear).
  // Global source column is the swizzled one: (colblock ^ (row&3))*16.
  const int s0 = wave * 64 + lane;
  const int s1 = s0 + 256;
  const int rA0 = s0 >> 2, cb0 = s0 & 3;
  const int rA1 = s1 >> 2, cb1 = s1 & 3;
  const int sc0 = (cb0 ^ (rA0 & 3)) << 4;
  const int sc1 = (cb1 ^ (rA1 & 3)) << 4;

  const uint8_t* ga0 = qa + (tile_m + rA0) * Kdim + sc0;
  const uint8_t* ga1 = qa + (tile_m + rA1) * Kdim + sc1;
  const uint8_t* gb0 = qb + (tile_n + rA0) * Kdim + sc0;
  const uint8_t* gb1 = qb + (tile_n + rA1) * Kdim + sc1;

  uint8_t* lA0 = As + wave * 1024;         // + implicit lane*16
  uint8_t* lA1 = As + 4096 + wave * 1024;
  uint8_t* lB0 = Bs + wave * 1024;
  uint8_t* lB1 = Bs + 4096 + wave * 1024;

  f32x4 acc[4][4] = {};

  const int lr = lane & 15;         // row (A) / col (B) within frag
  const int lk = (lane >> 4) * 8;   // k byte offset within 32-wide K slice

  for (int k0 = 0; k0 < Kdim; k0 += BK) {
    gload_lds16(ga0 + k0, lA0);
    gload_lds16(ga1 + k0, lA1);
    gload_lds16(gb0 + k0, lB0);
    gload_lds16(gb1 + k0, lB1);
    __syncthreads();   // compiler drains vmcnt before s_barrier

#pragma unroll
    for (int ks = 0; ks < 2; ++ks) {
      long long afr[4], bfr[4];
#pragma unroll
      for (int m = 0; m < 4; ++m) {
        const int row = wm * 64 + m * 16 + lr;
        afr[m] = *(const long long*)(As + row * BK + ((ks * 32 + lk) ^ ((row & 3) << 4)));
      }
#pragma unroll
      for (int n = 0; n < 4; ++n) {
        const int row = wn * 64 + n * 16 + lr;
        bfr[n] = *(const long long*)(Bs + row * BK + ((ks * 32 + lk) ^ ((row & 3) << 4)));
      }
#pragma unroll
      for (int m = 0; m < 4; ++m)
#pragma unroll
        for (int n = 0; n < 4; ++n)
          acc[m][n] = __builtin_amdgcn_mfma_f32_16x16x32_fp8_fp8(
              afr[m], bfr[n], acc[m][n], 0, 0, 0);
    }
    __syncthreads();   // protect LDS before next stage overwrites
  }

  const float alpha = iscale[0] * wscale[0];
  const long long col0 = tile_n + wn * 64 + lr;
  const long long row0 = tile_m + wm * 64 + (lane >> 4) * 4;
  float bv[4];
#pragma unroll
  for (int n = 0; n < 4; ++n) bv[n] = bias[col0 + n * 16];
#pragma unroll
  for (int m = 0; m < 4; ++m) {
#pragma unroll
    for (int r = 0; r < 4; ++r) {
      const long long row = row0 + m * 16 + r;
      float* op = out + row * (long long)Ndim + col0;
#pragma unroll
      for (int n = 0; n < 4; ++n)
        op[n * 16] = acc[m][n][r] * alpha + bv[n];
    }
  }
}

extern "C" void kernel_launch(void* const* d_in, const int* in_sizes, int n_in,
                              void* d_out, int out_size, void* d_ws, size_t ws_size,
                              hipStream_t stream) {
  const float* x      = (const float*)d_in[0];  // [4,2048,4096]
  const float* weight = (const float*)d_in[1];  // [14336,4096] (e4m3 lattice)
  const float* wscale = (const float*)d_in[2];  // [1]
  const float* iscale = (const float*)d_in[3];  // [1]
  const float* bias   = (const float*)d_in[4];  // [14336]
  float* out = (float*)d_out;                   // [4,2048,14336]

  uint8_t* qx = (uint8_t*)d_ws;                          // 32 MiB
  uint8_t* qw = qx + (long long)Mdim * Kdim;             // 56 MiB

  const long long nx = (long long)Mdim * Kdim;
  const long long nw = (long long)Ndim * Kdim;

  quant_fp8_kernel<<<4096, 256, 0, stream>>>(x, qx, iscale, nx);
  quant_fp8_kernel<<<4096, 256, 0, stream>>>(weight, qw, nullptr, nw);

  dim3 grid(Ndim / BN, Mdim / BM);
  gemm_fp8_kernel<<<grid, 256, 0, stream>>>(qx, qw, iscale, wscale, bias, out);
}

// Round 3
// 705.592 us; speedup vs baseline: 2.9058x; 1.7151x over previous
//
#include <hip/hip_runtime.h>
#include <stdint.h>

typedef float f32x4  __attribute__((ext_vector_type(4)));
typedef float f32x16 __attribute__((ext_vector_type(16)));
typedef int   i32x4  __attribute__((ext_vector_type(4)));
typedef int   i32x8  __attribute__((ext_vector_type(8)));

constexpr int Mdim = 8192;    // B*S = 4*2048
constexpr int Ndim = 14336;
constexpr int Kdim = 4096;
constexpr int BM = 128, BN = 128, BK = 64;

__device__ __forceinline__ void gload_lds16(const void* g, void* l) {
  __builtin_amdgcn_global_load_lds(
      (const __attribute__((address_space(1))) unsigned int*)g,
      (__attribute__((address_space(3))) unsigned int*)l, 16, 0, 0);
}

// Quantize fp32 -> fp8 e4m3fn (OCP, RNE via v_cvt_pk_fp8_f32):
//   q = cast(clip(v / s, -448, 448)).  Weight path: scale_ptr==nullptr
//   (s = 1.0, exact conversion since values are e4m3 lattice points).
__global__ void __launch_bounds__(256) quant_fp8_kernel(
    const float* __restrict__ in, uint8_t* __restrict__ out8,
    const float* __restrict__ scale_ptr, long long n)
{
  const float s = scale_ptr ? scale_ptr[0] : 1.0f;
  const long long nch = n >> 3;
  const long long idx = (long long)blockIdx.x * blockDim.x + threadIdx.x;
  const long long stride = (long long)gridDim.x * blockDim.x;
  for (long long c = idx; c < nch; c += stride) {
    f32x4 v0 = *(const f32x4*)(in + c * 8);
    f32x4 v1 = *(const f32x4*)(in + c * 8 + 4);
    float q[8];
#pragma unroll
    for (int j = 0; j < 4; ++j) {
      q[j]     = fminf(fmaxf(v0[j] / s, -448.f), 448.f);
      q[4 + j] = fminf(fmaxf(v1[j] / s, -448.f), 448.f);
    }
    unsigned int w0 = 0, w1 = 0;
    w0 = __builtin_amdgcn_cvt_pk_fp8_f32(q[0], q[1], w0, false);
    w0 = __builtin_amdgcn_cvt_pk_fp8_f32(q[2], q[3], w0, true);
    w1 = __builtin_amdgcn_cvt_pk_fp8_f32(q[4], q[5], w1, false);
    w1 = __builtin_amdgcn_cvt_pk_fp8_f32(q[6], q[7], w1, true);
    uint2 r; r.x = w0; r.y = w1;
    *(uint2*)(out8 + c * 8) = r;
  }
}

// C = (A @ B^T) * alpha + bias via MX-scaled fp8 MFMA with UNIT scales
// (e8m0 0x7F = 2^0 -> bit-identical to plain fp8 matmul, 2x rate).
// 128x128 tile, BK=64, 4 waves (2x2), each wave 64x64 via 2x2 frags of
// mfma_scale_f32_32x32x64_f8f6f4 (A/B fmt 0 = e4m3).
//
// Fragment layout (32x32x64): lane l -> row/col = l&31, k = (l>>5)*32 + j,
// j=0..31 contiguous (2x ds_read_b128 per fragment).
// T2 swizzle for 32B/lane reads: LDS logical byte (row,c) stored at
// row*64 + (c ^ (((row>>1)&3)<<4)).  Swizzle lives in byte bits [5:4] so each
// 16-B global_load_lds segment stays contiguous: pre-swizzle the GLOBAL source
// column, keep LDS dest linear, XOR on the read (both-sides, rule #21).
// Bank check: lane l -> parity e=l&1, t=(l>>1)&3, kh=l>>5; phys 16B-block
// p=(kh*2)^t -> each (e,p) 4-bank group gets exactly 8 lanes x 4 words
// = 8 words/bank = wave64 b128 floor.  Conflict-free.
__global__ void __launch_bounds__(256) gemm_fp8_kernel(
    const uint8_t* __restrict__ qa, const uint8_t* __restrict__ qb,
    const float* __restrict__ iscale, const float* __restrict__ wscale,
    const float* __restrict__ bias, float* __restrict__ out)
{
  __shared__ uint8_t As[BM * BK];
  __shared__ uint8_t Bs[BN * BK];

  const int tid  = threadIdx.x;
  const int wave = tid >> 6;
  const int lane = tid & 63;
  const int wm = wave >> 1;   // 0..1
  const int wn = wave & 1;    // 0..1
  const long long tile_m = (long long)blockIdx.y * BM;
  const long long tile_n = (long long)blockIdx.x * BN;

  // Staging: 512 16-byte segments per tile; segment s -> row = s>>2,
  // physical block pb = s&3; LDS offset = s*16 (linear).  Source column is
  // the logical block that belongs at pb: (pb ^ ((row>>1)&3))*16.
  const int s0 = wave * 64 + lane;
  const int s1 = s0 + 256;
  const int rA0 = s0 >> 2, cb0 = s0 & 3;
  const int rA1 = s1 >> 2, cb1 = s1 & 3;
  const int sc0 = (cb0 ^ ((rA0 >> 1) & 3)) << 4;
  const int sc1 = (cb1 ^ ((rA1 >> 1) & 3)) << 4;

  const uint8_t* ga0 = qa + (tile_m + rA0) * Kdim + sc0;
  const uint8_t* ga1 = qa + (tile_m + rA1) * Kdim + sc1;
  const uint8_t* gb0 = qb + (tile_n + rA0) * Kdim + sc0;
  const uint8_t* gb1 = qb + (tile_n + rA1) * Kdim + sc1;

  uint8_t* lA0 = As + wave * 1024;         // + implicit lane*16
  uint8_t* lA1 = As + 4096 + wave * 1024;
  uint8_t* lB0 = Bs + wave * 1024;
  uint8_t* lB1 = Bs + 4096 + wave * 1024;

  f32x16 acc[2][2] = {};

  const int col = lane & 31;   // row (A) / col (B) within 32x32 frag
  const int kh  = lane >> 5;   // k-half: this lane's k = kh*32 .. +32

  for (int k0 = 0; k0 < Kdim; k0 += BK) {
    gload_lds16(ga0 + k0, lA0);
    gload_lds16(ga1 + k0, lA1);
    gload_lds16(gb0 + k0, lB0);
    gload_lds16(gb1 + k0, lB1);
    __syncthreads();   // drains vmcnt before s_barrier

    i32x8 af[2], bf[2];
#pragma unroll
    for (int m = 0; m < 2; ++m) {
      const int row = wm * 64 + m * 32 + col;
      const int pc  = (kh * 32) ^ (((row >> 1) & 3) << 4);
      i32x4 lo = *(const i32x4*)(As + row * BK + pc);
      i32x4 hi = *(const i32x4*)(As + row * BK + (pc ^ 16));
      af[m] = __builtin_shufflevector(lo, hi, 0, 1, 2, 3, 4, 5, 6, 7);
    }
#pragma unroll
    for (int n = 0; n < 2; ++n) {
      const int row = wn * 64 + n * 32 + col;
      const int pc  = (kh * 32) ^ (((row >> 1) & 3) << 4);
      i32x4 lo = *(const i32x4*)(Bs + row * BK + pc);
      i32x4 hi = *(const i32x4*)(Bs + row * BK + (pc ^ 16));
      bf[n] = __builtin_shufflevector(lo, hi, 0, 1, 2, 3, 4, 5, 6, 7);
    }

#pragma unroll
    for (int m = 0; m < 2; ++m)
#pragma unroll
      for (int n = 0; n < 2; ++n)
        acc[m][n] = __builtin_amdgcn_mfma_scale_f32_32x32x64_f8f6f4(
            af[m], bf[n], acc[m][n], 0, 0,          // cbsz=0 (e4m3), blgp=0
            0, 0x7f7f7f7f, 0, 0x7f7f7f7f);          // unit scales (2^0)

    __syncthreads();   // protect LDS before next stage overwrites
  }

  // C/D layout (32x32, dtype-independent): col=lane&31,
  // row = (r&3) + 8*(r>>2) + 4*(lane>>5), r in [0,16).
  const float alpha = iscale[0] * wscale[0];
  const long long col0 = tile_n + wn * 64 + col;
  const float bv0 = bias[col0];
  const float bv1 = bias[col0 + 32];
#pragma unroll
  for (int m = 0; m < 2; ++m) {
#pragma unroll
    for (int r = 0; r < 16; ++r) {
      const long long row =
          tile_m + wm * 64 + m * 32 + (r & 3) + 8 * (r >> 2) + 4 * kh;
      float* op = out + row * (long long)Ndim + col0;
      op[0]  = acc[m][0][r] * alpha + bv0;
      op[32] = acc[m][1][r] * alpha + bv1;
    }
  }
}

extern "C" void kernel_launch(void* const* d_in, const int* in_sizes, int n_in,
                              void* d_out, int out_size, void* d_ws, size_t ws_size,
                              hipStream_t stream) {
  const float* x      = (const float*)d_in[0];  // [4,2048,4096]
  const float* weight = (const float*)d_in[1];  // [14336,4096] (e4m3 lattice)
  const float* wscale = (const float*)d_in[2];  // [1]
  const float* iscale = (const float*)d_in[3];  // [1]
  const float* bias   = (const float*)d_in[4];  // [14336]
  float* out = (float*)d_out;                   // [4,2048,14336]

  uint8_t* qx = (uint8_t*)d_ws;                          // 32 MiB
  uint8_t* qw = qx + (long long)Mdim * Kdim;             // 56 MiB

  const long long nx = (long long)Mdim * Kdim;
  const long long nw = (long long)Ndim * Kdim;

  quant_fp8_kernel<<<4096, 256, 0, stream>>>(x, qx, iscale, nx);
  quant_fp8_kernel<<<4096, 256, 0, stream>>>(weight, qw, nullptr, nw);

  dim3 grid(Ndim / BN, Mdim / BM);
  gemm_fp8_kernel<<<grid, 256, 0, stream>>>(qx, qw, iscale, wscale, bias, out);
}

// Round 4
// 522.808 us; speedup vs baseline: 3.9217x; 1.3496x over previous
//
#include <hip/hip_runtime.h>
#include <stdint.h>

typedef float f32x4  __attribute__((ext_vector_type(4)));
typedef float f32x16 __attribute__((ext_vector_type(16)));
typedef int   i32x4  __attribute__((ext_vector_type(4)));
typedef int   i32x8  __attribute__((ext_vector_type(8)));

constexpr int Mdim = 8192;    // B*S = 4*2048
constexpr int Ndim = 14336;
constexpr int Kdim = 4096;
constexpr int BM = 256, BN = 256, BK = 128;
constexpr int NT = Kdim / BK;        // 32 K-tiles
constexpr uint32_t BUFSZ = 65536;    // one buffer: A(32K) + B(32K)

#define VMCNT(n) asm volatile("s_waitcnt vmcnt(" #n ")" ::: "memory")
#define LGKM0()  do { asm volatile("s_waitcnt lgkmcnt(0)" ::: "memory"); \
                      __builtin_amdgcn_sched_barrier(0); } while (0)
#define BARRIER() do { asm volatile("" ::: "memory"); \
                       __builtin_amdgcn_s_barrier(); \
                       asm volatile("" ::: "memory"); } while (0)

__device__ __forceinline__ void gload_lds16(const void* g, void* l) {
  __builtin_amdgcn_global_load_lds(
      (const __attribute__((address_space(1))) unsigned int*)g,
      (__attribute__((address_space(3))) unsigned int*)l, 16, 0, 0);
}

__device__ __forceinline__ i32x4 ldsr128(const uint8_t* p) {
  i32x4 r;
  asm volatile("ds_read_b128 %0, %1"
               : "=v"(r)
               : "v"((const __attribute__((address_space(3))) uint8_t*)p));
  return r;
}

// Fragment read: 32 contiguous logical bytes (one 32x32x64 A/B frag per lane)
// at logical byte kb of row `row`; physical byte = logical ^ ((row&7)<<4).
__device__ __forceinline__ i32x8 frag(const uint8_t* tile, int row, int kb) {
  const int p0 = kb ^ ((row & 7) << 4);
  const uint8_t* rp = tile + row * BK;
  i32x4 lo = ldsr128(rp + p0);
  i32x4 hi = ldsr128(rp + (p0 ^ 16));
  return __builtin_shufflevector(lo, hi, 0, 1, 2, 3, 4, 5, 6, 7);
}

__device__ __forceinline__ f32x16 mx(i32x8 a, i32x8 b, f32x16 c) {
  // unit e8m0 scales (0x7f = 2^0): bit-identical to plain fp8 matmul, 2x rate
  return __builtin_amdgcn_mfma_scale_f32_32x32x64_f8f6f4(
      a, b, c, 0, 0, 0, 0x7f7f7f7f, 0, 0x7f7f7f7f);
}

// Quantize fp32 -> fp8 e4m3fn (OCP, RNE via v_cvt_pk_fp8_f32):
//   q = cast(clip(v / s, -448, 448)).  Weight path: scale_ptr==nullptr.
__global__ void __launch_bounds__(256) quant_fp8_kernel(
    const float* __restrict__ in, uint8_t* __restrict__ out8,
    const float* __restrict__ scale_ptr, long long n)
{
  const float s = scale_ptr ? scale_ptr[0] : 1.0f;
  const long long nch = n >> 3;
  const long long idx = (long long)blockIdx.x * blockDim.x + threadIdx.x;
  const long long stride = (long long)gridDim.x * blockDim.x;
  for (long long c = idx; c < nch; c += stride) {
    f32x4 v0 = *(const f32x4*)(in + c * 8);
    f32x4 v1 = *(const f32x4*)(in + c * 8 + 4);
    float q[8];
#pragma unroll
    for (int j = 0; j < 4; ++j) {
      q[j]     = fminf(fmaxf(v0[j] / s, -448.f), 448.f);
      q[4 + j] = fminf(fmaxf(v1[j] / s, -448.f), 448.f);
    }
    unsigned int w0 = 0, w1 = 0;
    w0 = __builtin_amdgcn_cvt_pk_fp8_f32(q[0], q[1], w0, false);
    w0 = __builtin_amdgcn_cvt_pk_fp8_f32(q[2], q[3], w0, true);
    w1 = __builtin_amdgcn_cvt_pk_fp8_f32(q[4], q[5], w1, false);
    w1 = __builtin_amdgcn_cvt_pk_fp8_f32(q[6], q[7], w1, true);
    uint2 r; r.x = w0; r.y = w1;
    *(uint2*)(out8 + c * 8) = r;
  }
}

// C = (A @ B^T) * alpha + bias, MX-fp8 unit-scale MFMA.
// 256x256 tile, BK=128, 8 waves (2M x 4N), per-wave 128x64 = 4x2 frags of
// 32x32x64.  8-phase-style schedule (T3+T4+T5): 4 phases per K-tile, 2
// global_load_lds issued per phase for tile t+1, ONE counted vmcnt(2) +
// barrier per tile (tile t+1's first loads stay in flight across it), end-of-
// tile barrier.  Raw s_barrier (no vmcnt drain), asm ds_reads + explicit
// lgkmcnt(0)+sched_barrier(0) (rule #18), setprio around MFMA clusters (T5).
//
// LDS: 2 buffers x (A 256x128 | B 256x128) = 128 KiB, row-major linear,
// T2 swizzle: physical 16B-block = logical ^ (row&7); applied by
// pre-swizzling the GLOBAL source column (dest stays linear for
// global_load_lds) and XOR-ing on the read (rule #21).  Bank check: a wave's
// b128 read has rows base+lane&31, phys block = cb ^ (row&7) -> every 16B
// block column gets 8 lanes x 4 words / 4 banks = 8 words/bank = floor.
__global__ void __launch_bounds__(512, 2) gemm_fp8_kernel(
    const uint8_t* __restrict__ qa, const uint8_t* __restrict__ qb,
    const float* __restrict__ iscale, const float* __restrict__ wscale,
    const float* __restrict__ bias, float* __restrict__ out)
{
  __shared__ uint8_t smem[2 * BUFSZ];   // 128 KiB

  const int tid  = threadIdx.x;
  const int wave = tid >> 6;
  const int lane = tid & 63;
  const int wm   = wave >> 2;       // 0..1
  const int wn   = wave & 3;        // 0..3
  const int col  = lane & 31;
  const int kh   = lane >> 5;
  const long long tile_m = (long long)blockIdx.y * BM;
  const long long tile_n = (long long)blockIdx.x * BN;

  // Staging: unit = 64 rows x 128 B = 8 KiB = 512 thr x 16 B (1 gload/thr).
  // A units 0..3 (rows u*64..), B units 0..3.  Thread -> row tid>>3, physical
  // block tid&7; global source block = pb ^ (row&7)  (row&7 == (tid>>3)&7).
  const int urow = tid >> 3;                   // 0..63
  const int pbs  = tid & 7;
  const int scol = (pbs ^ (urow & 7)) << 4;
  const uint8_t* gA = qa + (tile_m + urow) * Kdim + scol;
  const uint8_t* gB = qb + (tile_n + urow) * Kdim + scol;
  uint8_t* lbase = smem + wave * 1024;         // wave-uniform; + lane*16 by HW

#define STAGE(u, mat, k0, boff)                                           \
  gload_lds16((mat ? gB : gA) + (long long)(u) * 64 * Kdim + (k0),        \
              lbase + (boff) + (mat) * 32768 + (u) * 8192)

  f32x16 acc[4][2] = {};

  const int rowA = wm * 128 + col;   // + m*32
  const int rowB = wn * 64 + col;    // + n*32
  const int kb0 = kh * 32;           // ks=0 logical byte
  const int kb1 = 64 + kh * 32;      // ks=1

  // prologue: stage tile 0 into buffer 0 (8 loads in flight)
#pragma unroll
  for (int u = 0; u < 4; ++u) STAGE(u, 0, 0, 0);
#pragma unroll
  for (int u = 0; u < 4; ++u) STAGE(u, 1, 0, 0);

  uint32_t cur = 0;
  for (int t = 0; t < NT - 1; ++t) {
    const long long kn = (long long)(t + 1) * BK;
    const uint32_t nxt = cur ^ BUFSZ;
    const uint8_t* Ab = smem + cur;
    const uint8_t* Bb = smem + cur + 32768;

    // ---- P0: ks=0, m={0,1} ----
    STAGE(0, 0, kn, nxt); STAGE(1, 0, kn, nxt);
    VMCNT(2);             // tile t's 8 loads retired; t+1's 2 stay in flight
    BARRIER();            // all waves: buf[cur] tile-t data visible
    i32x8 a0 = frag(Ab, rowA +  0, kb0);
    i32x8 a1 = frag(Ab, rowA + 32, kb0);
    i32x8 b0 = frag(Bb, rowB +  0, kb0);
    i32x8 b1 = frag(Bb, rowB + 32, kb0);
    LGKM0();
    __builtin_amdgcn_s_setprio(1);
    acc[0][0] = mx(a0, b0, acc[0][0]);  acc[0][1] = mx(a0, b1, acc[0][1]);
    acc[1][0] = mx(a1, b0, acc[1][0]);  acc[1][1] = mx(a1, b1, acc[1][1]);
    __builtin_amdgcn_s_setprio(0);

    // ---- P1: ks=0, m={2,3} ----
    STAGE(2, 0, kn, nxt); STAGE(3, 0, kn, nxt);
    a0 = frag(Ab, rowA + 64, kb0);
    a1 = frag(Ab, rowA + 96, kb0);
    LGKM0();
    __builtin_amdgcn_s_setprio(1);
    acc[2][0] = mx(a0, b0, acc[2][0]);  acc[2][1] = mx(a0, b1, acc[2][1]);
    acc[3][0] = mx(a1, b0, acc[3][0]);  acc[3][1] = mx(a1, b1, acc[3][1]);
    __builtin_amdgcn_s_setprio(0);

    // ---- P2: ks=1, m={0,1} ----
    STAGE(0, 1, kn, nxt); STAGE(1, 1, kn, nxt);
    a0 = frag(Ab, rowA +  0, kb1);
    a1 = frag(Ab, rowA + 32, kb1);
    b0 = frag(Bb, rowB +  0, kb1);
    b1 = frag(Bb, rowB + 32, kb1);
    LGKM0();
    __builtin_amdgcn_s_setprio(1);
    acc[0][0] = mx(a0, b0, acc[0][0]);  acc[0][1] = mx(a0, b1, acc[0][1]);
    acc[1][0] = mx(a1, b0, acc[1][0]);  acc[1][1] = mx(a1, b1, acc[1][1]);
    __builtin_amdgcn_s_setprio(0);

    // ---- P3: ks=1, m={2,3} ----
    STAGE(2, 1, kn, nxt); STAGE(3, 1, kn, nxt);
    a0 = frag(Ab, rowA + 64, kb1);
    a1 = frag(Ab, rowA + 96, kb1);
    LGKM0();
    __builtin_amdgcn_s_setprio(1);
    acc[2][0] = mx(a0, b0, acc[2][0]);  acc[2][1] = mx(a0, b1, acc[2][1]);
    acc[3][0] = mx(a1, b0, acc[3][0]);  acc[3][1] = mx(a1, b1, acc[3][1]);
    __builtin_amdgcn_s_setprio(0);
    BARRIER();            // all waves done reading buf[cur]

    cur = nxt;
  }

  // ---- tail tile NT-1 (no prefetch) ----
  {
    const uint8_t* Ab = smem + cur;
    const uint8_t* Bb = smem + cur + 32768;
    VMCNT(0);
    BARRIER();
#pragma unroll
    for (int ks = 0; ks < 2; ++ks) {
      const int kb = ks * 64 + kh * 32;
      i32x8 b0 = frag(Bb, rowB +  0, kb);
      i32x8 b1 = frag(Bb, rowB + 32, kb);
#pragma unroll
      for (int m = 0; m < 4; ++m) {
        i32x8 a = frag(Ab, rowA + m * 32, kb);
        LGKM0();
        acc[m][0] = mx(a, b0, acc[m][0]);
        acc[m][1] = mx(a, b1, acc[m][1]);
      }
    }
  }

  // Epilogue.  C/D layout (32x32, dtype-independent): col = lane&31,
  // row = (r&3) + 8*(r>>2) + 4*kh, r in [0,16).
  const float alpha = iscale[0] * wscale[0];
  const long long col0 = tile_n + wn * 64 + col;
  const float bv0 = bias[col0];
  const float bv1 = bias[col0 + 32];
#pragma unroll
  for (int m = 0; m < 4; ++m) {
#pragma unroll
    for (int r = 0; r < 16; ++r) {
      const long long row =
          tile_m + wm * 128 + m * 32 + (r & 3) + 8 * (r >> 2) + 4 * kh;
      float* op = out + row * (long long)Ndim + col0;
      op[0]  = acc[m][0][r] * alpha + bv0;
      op[32] = acc[m][1][r] * alpha + bv1;
    }
  }
#undef STAGE
}

extern "C" void kernel_launch(void* const* d_in, const int* in_sizes, int n_in,
                              void* d_out, int out_size, void* d_ws, size_t ws_size,
                              hipStream_t stream) {
  const float* x      = (const float*)d_in[0];  // [4,2048,4096]
  const float* weight = (const float*)d_in[1];  // [14336,4096] (e4m3 lattice)
  const float* wscale = (const float*)d_in[2];  // [1]
  const float* iscale = (const float*)d_in[3];  // [1]
  const float* bias   = (const float*)d_in[4];  // [14336]
  float* out = (float*)d_out;                   // [4,2048,14336]

  uint8_t* qx = (uint8_t*)d_ws;                          // 32 MiB
  uint8_t* qw = qx + (long long)Mdim * Kdim;             // 56 MiB

  const long long nx = (long long)Mdim * Kdim;
  const long long nw = (long long)Ndim * Kdim;

  quant_fp8_kernel<<<4096, 256, 0, stream>>>(x, qx, iscale, nx);
  quant_fp8_kernel<<<4096, 256, 0, stream>>>(weight, qw, nullptr, nw);

  dim3 grid(Ndim / BN, Mdim / BM);   // 56 x 32
  gemm_fp8_kernel<<<grid, 512, 0, stream>>>(qx, qw, iscale, wscale, bias, out);
}